// Round 1
// baseline (1377.326 us; speedup 1.0000x reference)
//
#include <hip/hip_runtime.h>
#include <math.h>

#define TT 8192   // tokens = B*P
#define NE 8      // experts
#define DIN 1024  // input size
#define DH 512    // hidden size

// ---------------- workspace layout (bytes) ----------------
// counts:    int[8]              @ 0
// base:      int[8]              @ 256
// tok_list:  int[8][8192]        @ 512
// gate_list: float[8][8192]      @ 512 + 256K
// h:         float[16384][512]   @ 512 + 512K   (~33.5 MB)
static const size_t OFF_CNT  = 0;
static const size_t OFF_BASE = 256;
static const size_t OFF_TOK  = 512;
static const size_t OFF_GATE = OFF_TOK  + (size_t)NE * TT * 4;
static const size_t OFF_H    = OFF_GATE + (size_t)NE * TT * 4;

// ---------------- gating: scores -> softmax -> top2 -> compaction ----------------
__global__ __launch_bounds__(256) void gate_kernel(
    const float* __restrict__ Q, const float* __restrict__ K,
    int* __restrict__ cnt, int* __restrict__ tok_list, float* __restrict__ gate_list)
{
    int t = blockIdx.x;
    int tid = threadIdx.x;
    const float4* q4 = reinterpret_cast<const float4*>(Q + (size_t)t * DIN);
    const float4* k4 = reinterpret_cast<const float4*>(K + (size_t)t * NE * DIN);
    float4 q = q4[tid];
    float part[NE];
#pragma unroll
    for (int e = 0; e < NE; ++e) {
        float4 kv = k4[e * (DIN / 4) + tid];
        part[e] = q.x * kv.x + q.y * kv.y + q.z * kv.z + q.w * kv.w;
    }
#pragma unroll
    for (int e = 0; e < NE; ++e) {
        float v = part[e];
        v += __shfl_down(v, 32);
        v += __shfl_down(v, 16);
        v += __shfl_down(v, 8);
        v += __shfl_down(v, 4);
        v += __shfl_down(v, 2);
        v += __shfl_down(v, 1);
        part[e] = v;
    }
    __shared__ float sm[4][NE];
    int wave = tid >> 6, lane = tid & 63;
    if (lane == 0) {
#pragma unroll
        for (int e = 0; e < NE; ++e) sm[wave][e] = part[e];
    }
    __syncthreads();
    if (tid == 0) {
        float s[NE];
#pragma unroll
        for (int e = 0; e < NE; ++e) {
            float v = (sm[0][e] + sm[1][e] + sm[2][e] + sm[3][e]) * 0.03125f;
            if (isnan(v)) v = 0.0f;
            else if (isinf(v)) v = (v > 0.0f) ? 20.0f : -20.0f;
            s[e] = v;
        }
        float m = s[0];
        for (int e = 1; e < NE; ++e) m = fmaxf(m, s[e]);
        float p[NE]; float sum = 0.0f;
        for (int e = 0; e < NE; ++e) { p[e] = expf(s[e] - m); sum += p[e]; }
        float inv = 1.0f / sum;
        for (int e = 0; e < NE; ++e) p[e] *= inv;
        int i0 = 0;
        for (int e = 1; e < NE; ++e) if (p[e] > p[i0]) i0 = e;
        int i1 = (i0 == 0) ? 1 : 0;
        for (int e = 0; e < NE; ++e) if (e != i0 && p[e] > p[i1]) i1 = e;
        float denom = p[i0] + p[i1] + 1e-6f;
        float g0 = p[i0] / denom, g1 = p[i1] / denom;
        int pos0 = atomicAdd(&cnt[i0], 1);
        tok_list[i0 * TT + pos0] = t; gate_list[i0 * TT + pos0] = g0;
        int pos1 = atomicAdd(&cnt[i1], 1);
        tok_list[i1 * TT + pos1] = t; gate_list[i1 * TT + pos1] = g1;
    }
}

// ---------------- tiny exclusive scan over 8 counts ----------------
__global__ void scan_kernel(const int* __restrict__ cnt, int* __restrict__ base)
{
    if (threadIdx.x == 0) {
        int s = 0;
        for (int e = 0; e < NE; ++e) { base[e] = s; s += cnt[e]; }
    }
}

// ---------------- GEMM1: h = gelu(x_gathered @ w1[e]) ----------------
__global__ __launch_bounds__(256) void gemm1_kernel(
    const float* __restrict__ x, const float* __restrict__ w1,
    const int* __restrict__ cnt, const int* __restrict__ base,
    const int* __restrict__ tok_list, float* __restrict__ h)
{
    int e = blockIdx.z;
    int Te = cnt[e];
    int m0 = blockIdx.x * 64;
    if (m0 >= Te) return;
    int n0 = blockIdx.y * 128;

    __shared__ float As[32][68];    // k-major: As[kk][r]
    __shared__ float Bs[32][132];   // Bs[kk][c]
    __shared__ int rows[64];

    int tid = threadIdx.x;
    if (tid < 64) rows[tid] = (m0 + tid < Te) ? tok_list[e * TT + m0 + tid] : -1;
    __syncthreads();

    float acc[4][8];
#pragma unroll
    for (int i = 0; i < 4; i++)
#pragma unroll
        for (int j = 0; j < 8; j++) acc[i][j] = 0.0f;

    int tr = (tid >> 4) * 4;
    int tc = (tid & 15) * 8;
    int sr = tid >> 2;
    int sk = (tid & 3) * 8;
    int br = tid >> 3;
    int bc = (tid & 7) * 16;
    const float* w1e = w1 + (size_t)e * DIN * DH;

    for (int k0 = 0; k0 < DIN; k0 += 32) {
        int trow = rows[sr];
        float4 a0 = {0, 0, 0, 0}, a1 = {0, 0, 0, 0};
        if (trow >= 0) {
            const float4* xp = reinterpret_cast<const float4*>(x + (size_t)trow * DIN + k0 + sk);
            a0 = xp[0]; a1 = xp[1];
        }
        const float4* wp = reinterpret_cast<const float4*>(w1e + (size_t)(k0 + br) * DH + n0 + bc);
        float4 b0 = wp[0], b1 = wp[1], b2 = wp[2], b3 = wp[3];
        __syncthreads();
        As[sk + 0][sr] = a0.x; As[sk + 1][sr] = a0.y; As[sk + 2][sr] = a0.z; As[sk + 3][sr] = a0.w;
        As[sk + 4][sr] = a1.x; As[sk + 5][sr] = a1.y; As[sk + 6][sr] = a1.z; As[sk + 7][sr] = a1.w;
        *reinterpret_cast<float4*>(&Bs[br][bc + 0])  = b0;
        *reinterpret_cast<float4*>(&Bs[br][bc + 4])  = b1;
        *reinterpret_cast<float4*>(&Bs[br][bc + 8])  = b2;
        *reinterpret_cast<float4*>(&Bs[br][bc + 12]) = b3;
        __syncthreads();
#pragma unroll
        for (int kk = 0; kk < 32; ++kk) {
            float4 av  = *reinterpret_cast<const float4*>(&As[kk][tr]);
            float4 bv0 = *reinterpret_cast<const float4*>(&Bs[kk][tc]);
            float4 bv1 = *reinterpret_cast<const float4*>(&Bs[kk][tc + 4]);
            float a[4] = {av.x, av.y, av.z, av.w};
            float b[8] = {bv0.x, bv0.y, bv0.z, bv0.w, bv1.x, bv1.y, bv1.z, bv1.w};
#pragma unroll
            for (int i = 0; i < 4; i++)
#pragma unroll
                for (int j = 0; j < 8; j++)
                    acc[i][j] = fmaf(a[i], b[j], acc[i][j]);
        }
    }

    int hb = base[e] + m0;
#pragma unroll
    for (int i = 0; i < 4; i++) {
        int r = tr + i;
        if (m0 + r < Te) {
            float* hp = h + (size_t)(hb + r) * DH + n0 + tc;
            float v[8];
#pragma unroll
            for (int j = 0; j < 8; j++) {
                float u = acc[i][j];
                v[j] = 0.5f * u * (1.0f + erff(u * 0.70710678118f));  // exact gelu
            }
            *reinterpret_cast<float4*>(hp)     = make_float4(v[0], v[1], v[2], v[3]);
            *reinterpret_cast<float4*>(hp + 4) = make_float4(v[4], v[5], v[6], v[7]);
        }
    }
}

// ---------------- GEMM2: out += gate * (h @ w2[e]) ----------------
__global__ __launch_bounds__(256) void gemm2_kernel(
    const float* __restrict__ h, const float* __restrict__ w2,
    const int* __restrict__ cnt, const int* __restrict__ base,
    const int* __restrict__ tok_list, const float* __restrict__ gate_list,
    float* __restrict__ out)
{
    int e = blockIdx.z;
    int Te = cnt[e];
    int m0 = blockIdx.x * 64;
    if (m0 >= Te) return;
    int n0 = blockIdx.y * 128;

    __shared__ float As[32][68];
    __shared__ float Bs[32][132];
    __shared__ int toks[64];
    __shared__ float gts[64];

    int tid = threadIdx.x;
    if (tid < 64) {
        bool v = (m0 + tid < Te);
        toks[tid] = v ? tok_list[e * TT + m0 + tid] : -1;
        gts[tid]  = v ? gate_list[e * TT + m0 + tid] : 0.0f;
    }
    __syncthreads();

    float acc[4][8];
#pragma unroll
    for (int i = 0; i < 4; i++)
#pragma unroll
        for (int j = 0; j < 8; j++) acc[i][j] = 0.0f;

    int tr = (tid >> 4) * 4;
    int tc = (tid & 15) * 8;
    int sr = tid >> 2;
    int sk = (tid & 3) * 8;
    int br = tid >> 3;
    int bc = (tid & 7) * 16;
    int hb = base[e];
    const float* w2e = w2 + (size_t)e * DH * DIN;

    for (int k0 = 0; k0 < DH; k0 += 32) {
        float4 a0 = {0, 0, 0, 0}, a1 = {0, 0, 0, 0};
        if (m0 + sr < Te) {
            const float4* hp = reinterpret_cast<const float4*>(h + (size_t)(hb + m0 + sr) * DH + k0 + sk);
            a0 = hp[0]; a1 = hp[1];
        }
        const float4* wp = reinterpret_cast<const float4*>(w2e + (size_t)(k0 + br) * DIN + n0 + bc);
        float4 b0 = wp[0], b1 = wp[1], b2 = wp[2], b3 = wp[3];
        __syncthreads();
        As[sk + 0][sr] = a0.x; As[sk + 1][sr] = a0.y; As[sk + 2][sr] = a0.z; As[sk + 3][sr] = a0.w;
        As[sk + 4][sr] = a1.x; As[sk + 5][sr] = a1.y; As[sk + 6][sr] = a1.z; As[sk + 7][sr] = a1.w;
        *reinterpret_cast<float4*>(&Bs[br][bc + 0])  = b0;
        *reinterpret_cast<float4*>(&Bs[br][bc + 4])  = b1;
        *reinterpret_cast<float4*>(&Bs[br][bc + 8])  = b2;
        *reinterpret_cast<float4*>(&Bs[br][bc + 12]) = b3;
        __syncthreads();
#pragma unroll
        for (int kk = 0; kk < 32; ++kk) {
            float4 av  = *reinterpret_cast<const float4*>(&As[kk][tr]);
            float4 bv0 = *reinterpret_cast<const float4*>(&Bs[kk][tc]);
            float4 bv1 = *reinterpret_cast<const float4*>(&Bs[kk][tc + 4]);
            float a[4] = {av.x, av.y, av.z, av.w};
            float b[8] = {bv0.x, bv0.y, bv0.z, bv0.w, bv1.x, bv1.y, bv1.z, bv1.w};
#pragma unroll
            for (int i = 0; i < 4; i++)
#pragma unroll
                for (int j = 0; j < 8; j++)
                    acc[i][j] = fmaf(a[i], b[j], acc[i][j]);
        }
    }

#pragma unroll
    for (int i = 0; i < 4; i++) {
        int r = tr + i;
        if (m0 + r < Te) {
            float g = gts[r];
            int t = toks[r];
            float* op = out + (size_t)t * DIN + n0 + tc;
#pragma unroll
            for (int j = 0; j < 8; j++) atomicAdd(op + j, acc[i][j] * g);
        }
    }
}

extern "C" void kernel_launch(void* const* d_in, const int* in_sizes, int n_in,
                              void* d_out, int out_size, void* d_ws, size_t ws_size,
                              hipStream_t stream) {
    const float* x  = (const float*)d_in[0];
    const float* Q  = (const float*)d_in[1];
    const float* K  = (const float*)d_in[2];
    const float* w1 = (const float*)d_in[3];
    const float* w2 = (const float*)d_in[4];
    float* out = (float*)d_out;

    char* ws = (char*)d_ws;
    int*   cnt       = (int*)(ws + OFF_CNT);
    int*   base      = (int*)(ws + OFF_BASE);
    int*   tok_list  = (int*)(ws + OFF_TOK);
    float* gate_list = (float*)(ws + OFF_GATE);
    float* h         = (float*)(ws + OFF_H);

    // zero counts + output accumulator (ws/out are poisoned before every call)
    hipMemsetAsync(ws + OFF_CNT, 0, 64, stream);
    hipMemsetAsync(d_out, 0, (size_t)out_size * sizeof(float), stream);

    gate_kernel<<<TT, 256, 0, stream>>>(Q, K, cnt, tok_list, gate_list);
    scan_kernel<<<1, 64, 0, stream>>>(cnt, base);
    gemm1_kernel<<<dim3(TT / 64, DH / 128, NE), 256, 0, stream>>>(x, w1, cnt, base, tok_list, h);
    gemm2_kernel<<<dim3(TT / 64, DIN / 128, NE), 256, 0, stream>>>(h, w2, cnt, base, tok_list, gate_list, out);
}

// Round 2
// 728.856 us; speedup vs baseline: 1.8897x; 1.8897x over previous
//
#include <hip/hip_runtime.h>
#include <math.h>

#define TT 8192   // tokens = B*P
#define NE 8      // experts
#define DIN 1024  // input size
#define DH 512    // hidden size

typedef __attribute__((ext_vector_type(8))) short short8;   // 8 bf16 = 4 VGPRs
typedef __attribute__((ext_vector_type(4))) float f32x4;
typedef __attribute__((ext_vector_type(4))) unsigned short us4;

// ---------------- workspace layout (bytes) ----------------
static const size_t OFF_CNT    = 0;                                   // int[8]
static const size_t OFF_BASE   = 256;                                 // int[8]
static const size_t OFF_TOKEXP = 512;                                 // int4[TT]
static const size_t OFF_TOK    = OFF_TOKEXP + (size_t)TT * 16;        // int[NE][TT]
static const size_t OFF_GATE   = OFF_TOK    + (size_t)NE * TT * 4;    // float[NE][TT]
static const size_t OFF_XB     = OFF_GATE   + (size_t)NE * TT * 4;    // bf16[TT][DIN]
static const size_t OFF_W1T    = OFF_XB     + (size_t)TT * DIN * 2;   // bf16[NE][DH][DIN]
static const size_t OFF_W2T    = OFF_W1T    + (size_t)NE * DH * DIN * 2; // bf16[NE][DIN][DH]
static const size_t OFF_H      = OFF_W2T    + (size_t)NE * DIN * DH * 2; // bf16[2*TT][DH]
static const size_t OFF_Y      = OFF_H      + (size_t)2 * TT * DH * 2;   // bf16[2*TT][DIN]

__device__ __forceinline__ unsigned short f2bf(float f) {
    union { float f; unsigned u; } v; v.f = f;
    unsigned r = (v.u + 0x7fffu + ((v.u >> 16) & 1u)) >> 16;
    return (unsigned short)r;
}
__device__ __forceinline__ float bf2f(unsigned short u) {
    union { unsigned u; float f; } v; v.u = ((unsigned)u) << 16;
    return v.f;
}
__device__ __forceinline__ void async_copy16(const void* g, void* l) {
    __builtin_amdgcn_global_load_lds(
        (const __attribute__((address_space(1))) void*)g,
        (__attribute__((address_space(3))) void*)l, 16, 0, 0);
}

// ---------------- conversions ----------------
__global__ __launch_bounds__(256) void convert_x_kernel(const float* __restrict__ x,
                                                        unsigned short* __restrict__ xb)
{
    size_t i = ((size_t)blockIdx.x * 256 + threadIdx.x) * 8;
    float4 a = *reinterpret_cast<const float4*>(x + i);
    float4 b = *reinterpret_cast<const float4*>(x + i + 4);
    us4 o0 = { f2bf(a.x), f2bf(a.y), f2bf(a.z), f2bf(a.w) };
    us4 o1 = { f2bf(b.x), f2bf(b.y), f2bf(b.z), f2bf(b.w) };
    *reinterpret_cast<us4*>(xb + i)     = o0;
    *reinterpret_cast<us4*>(xb + i + 4) = o1;
}

// src [E][K][N] fp32 -> dst [E][N][K] bf16
__global__ __launch_bounds__(256) void convert_w_kernel(const float* __restrict__ src,
                                                        unsigned short* __restrict__ dst,
                                                        int K, int N)
{
    int e = blockIdx.z;
    int k0 = blockIdx.x * 32, n0 = blockIdx.y * 32;
    __shared__ float tile[32][33];
    int tx = threadIdx.x & 31, ty = threadIdx.x >> 5;
    const float* s = src + ((size_t)e * K + k0) * N + n0;
#pragma unroll
    for (int r = 0; r < 32; r += 8) tile[ty + r][tx] = s[(size_t)(ty + r) * N + tx];
    __syncthreads();
    unsigned short* d = dst + ((size_t)e * N + n0) * K + k0;
#pragma unroll
    for (int r = 0; r < 32; r += 8) d[(size_t)(ty + r) * K + tx] = f2bf(tile[tx][ty + r]);
}

// ---------------- gating ----------------
__global__ __launch_bounds__(256) void gate_kernel(
    const float* __restrict__ Q, const float* __restrict__ K,
    int* __restrict__ cnt, int* __restrict__ tok_list, float* __restrict__ gate_list,
    int4* __restrict__ tokexp)
{
    int t = blockIdx.x;
    int tid = threadIdx.x;
    const float4* q4 = reinterpret_cast<const float4*>(Q + (size_t)t * DIN);
    const float4* k4 = reinterpret_cast<const float4*>(K + (size_t)t * NE * DIN);
    float4 q = q4[tid];
    float part[NE];
#pragma unroll
    for (int e = 0; e < NE; ++e) {
        float4 kv = k4[e * (DIN / 4) + tid];
        part[e] = q.x * kv.x + q.y * kv.y + q.z * kv.z + q.w * kv.w;
    }
#pragma unroll
    for (int e = 0; e < NE; ++e) {
        float v = part[e];
        v += __shfl_down(v, 32); v += __shfl_down(v, 16); v += __shfl_down(v, 8);
        v += __shfl_down(v, 4);  v += __shfl_down(v, 2);  v += __shfl_down(v, 1);
        part[e] = v;
    }
    __shared__ float sm[4][NE];
    int wave = tid >> 6, lane = tid & 63;
    if (lane == 0) {
#pragma unroll
        for (int e = 0; e < NE; ++e) sm[wave][e] = part[e];
    }
    __syncthreads();
    if (tid == 0) {
        float s[NE];
#pragma unroll
        for (int e = 0; e < NE; ++e) {
            float v = (sm[0][e] + sm[1][e] + sm[2][e] + sm[3][e]) * 0.03125f;
            if (isnan(v)) v = 0.0f;
            else if (isinf(v)) v = (v > 0.0f) ? 20.0f : -20.0f;
            s[e] = v;
        }
        float m = s[0];
        for (int e = 1; e < NE; ++e) m = fmaxf(m, s[e]);
        float p[NE]; float sum = 0.0f;
        for (int e = 0; e < NE; ++e) { p[e] = expf(s[e] - m); sum += p[e]; }
        float inv = 1.0f / sum;
        for (int e = 0; e < NE; ++e) p[e] *= inv;
        int i0 = 0;
        for (int e = 1; e < NE; ++e) if (p[e] > p[i0]) i0 = e;
        int i1 = (i0 == 0) ? 1 : 0;
        for (int e = 0; e < NE; ++e) if (e != i0 && p[e] > p[i1]) i1 = e;
        float denom = p[i0] + p[i1] + 1e-6f;
        float g0 = p[i0] / denom, g1 = p[i1] / denom;
        int pos0 = atomicAdd(&cnt[i0], 1);
        tok_list[i0 * TT + pos0] = t; gate_list[i0 * TT + pos0] = g0;
        int pos1 = atomicAdd(&cnt[i1], 1);
        tok_list[i1 * TT + pos1] = t; gate_list[i1 * TT + pos1] = g1;
        tokexp[t] = make_int4(i0, pos0, i1, pos1);
    }
}

__global__ void scan_kernel(const int* __restrict__ cnt, int* __restrict__ base)
{
    if (threadIdx.x == 0) {
        int s = 0;
        for (int e = 0; e < NE; ++e) { base[e] = s; s += cnt[e]; }
    }
}

// ---------------- GEMM1: h = gelu(gather(xb) @ w1t^T), bf16 MFMA ----------------
// 128x128 block tile, BK=32, 4 waves (2x2 of 64x64), LDS in fragment order.
__global__ __launch_bounds__(256) void gemm1_kernel(
    const unsigned short* __restrict__ xb, const unsigned short* __restrict__ w1t,
    const int* __restrict__ cnt, const int* __restrict__ base,
    const int* __restrict__ tok_list, unsigned short* __restrict__ h)
{
    int e = blockIdx.z;
    int Te = cnt[e];
    int m0 = blockIdx.x * 128;
    if (m0 >= Te) return;
    int n0 = blockIdx.y * 128;

    __shared__ __align__(16) char smem[16384];   // A: 8x1024B, B: 8x1024B
    __shared__ int rows[128];
    char* As = smem;
    char* Bs = smem + 8192;

    int tid = threadIdx.x;
    if (tid < 128) rows[tid] = (m0 + tid < Te) ? tok_list[e * TT + m0 + tid] : 0;
    __syncthreads();

    int w = tid >> 6, lane = tid & 63;
    int wm = w & 1, wn = w >> 1;
    int mcol = lane & 15;           // fragment row/col within 16-tile
    int kq = (lane >> 4) * 8;       // fragment k offset

    const unsigned short* w1e = w1t + (size_t)e * DH * DIN;
    const unsigned short* pa0 = xb + (size_t)rows[(2 * w + 0) * 16 + mcol] * DIN + kq;
    const unsigned short* pa1 = xb + (size_t)rows[(2 * w + 1) * 16 + mcol] * DIN + kq;
    const unsigned short* pb0 = w1e + (size_t)(n0 + (2 * w + 0) * 16 + mcol) * DIN + kq;
    const unsigned short* pb1 = w1e + (size_t)(n0 + (2 * w + 1) * 16 + mcol) * DIN + kq;
    char* dA0 = As + (2 * w + 0) * 1024;
    char* dA1 = As + (2 * w + 1) * 1024;
    char* dB0 = Bs + (2 * w + 0) * 1024;
    char* dB1 = Bs + (2 * w + 1) * 1024;

    f32x4 acc[4][4];
#pragma unroll
    for (int i = 0; i < 4; i++)
#pragma unroll
        for (int j = 0; j < 4; j++) acc[i][j] = {0.f, 0.f, 0.f, 0.f};

    for (int k0 = 0; k0 < DIN; k0 += 32) {
        __syncthreads();
        async_copy16(pa0, dA0); async_copy16(pa1, dA1);
        async_copy16(pb0, dB0); async_copy16(pb1, dB1);
        pa0 += 32; pa1 += 32; pb0 += 32; pb1 += 32;
        __syncthreads();
        short8 af[4], bfr[4];
#pragma unroll
        for (int mt = 0; mt < 4; ++mt)
            af[mt] = *reinterpret_cast<const short8*>(As + (wm * 4 + mt) * 1024 + lane * 16);
#pragma unroll
        for (int nt = 0; nt < 4; ++nt)
            bfr[nt] = *reinterpret_cast<const short8*>(Bs + (wn * 4 + nt) * 1024 + lane * 16);
#pragma unroll
        for (int mt = 0; mt < 4; ++mt)
#pragma unroll
            for (int nt = 0; nt < 4; ++nt)
                acc[mt][nt] = __builtin_amdgcn_mfma_f32_16x16x32_bf16(af[mt], bfr[nt], acc[mt][nt], 0, 0, 0);
    }

    int hb = base[e] + m0;
#pragma unroll
    for (int mt = 0; mt < 4; ++mt) {
        int rbase = (wm * 4 + mt) * 16 + ((lane >> 4) * 4);
#pragma unroll
        for (int r = 0; r < 4; ++r) {
            int row = rbase + r;
            if (m0 + row < Te) {
#pragma unroll
                for (int nt = 0; nt < 4; ++nt) {
                    float u = acc[mt][nt][r];
                    float g = 0.5f * u * (1.0f + erff(u * 0.70710678118f));
                    int col = n0 + (wn * 4 + nt) * 16 + mcol;
                    h[(size_t)(hb + row) * DH + col] = f2bf(g);
                }
            }
        }
    }
}

// ---------------- GEMM2: y = gate * (h @ w2t^T), bf16 MFMA ----------------
__global__ __launch_bounds__(256) void gemm2_kernel(
    const unsigned short* __restrict__ h, const unsigned short* __restrict__ w2t,
    const int* __restrict__ cnt, const int* __restrict__ base,
    const float* __restrict__ gate_list, unsigned short* __restrict__ y)
{
    int e = blockIdx.z;
    int Te = cnt[e];
    int m0 = blockIdx.x * 128;
    if (m0 >= Te) return;
    int n0 = blockIdx.y * 128;

    __shared__ __align__(16) char smem[16384];
    __shared__ float gts[128];
    char* As = smem;
    char* Bs = smem + 8192;

    int tid = threadIdx.x;
    if (tid < 128) gts[tid] = (m0 + tid < Te) ? gate_list[e * TT + m0 + tid] : 0.0f;

    int w = tid >> 6, lane = tid & 63;
    int wm = w & 1, wn = w >> 1;
    int mcol = lane & 15;
    int kq = (lane >> 4) * 8;
    int hb = base[e];

    int r0 = m0 + (2 * w + 0) * 16 + mcol; if (r0 >= Te) r0 = Te - 1;
    int r1 = m0 + (2 * w + 1) * 16 + mcol; if (r1 >= Te) r1 = Te - 1;
    const unsigned short* w2e = w2t + (size_t)e * DIN * DH;
    const unsigned short* pa0 = h + (size_t)(hb + r0) * DH + kq;
    const unsigned short* pa1 = h + (size_t)(hb + r1) * DH + kq;
    const unsigned short* pb0 = w2e + (size_t)(n0 + (2 * w + 0) * 16 + mcol) * DH + kq;
    const unsigned short* pb1 = w2e + (size_t)(n0 + (2 * w + 1) * 16 + mcol) * DH + kq;
    char* dA0 = As + (2 * w + 0) * 1024;
    char* dA1 = As + (2 * w + 1) * 1024;
    char* dB0 = Bs + (2 * w + 0) * 1024;
    char* dB1 = Bs + (2 * w + 1) * 1024;

    f32x4 acc[4][4];
#pragma unroll
    for (int i = 0; i < 4; i++)
#pragma unroll
        for (int j = 0; j < 4; j++) acc[i][j] = {0.f, 0.f, 0.f, 0.f};

    for (int k0 = 0; k0 < DH; k0 += 32) {
        __syncthreads();
        async_copy16(pa0, dA0); async_copy16(pa1, dA1);
        async_copy16(pb0, dB0); async_copy16(pb1, dB1);
        pa0 += 32; pa1 += 32; pb0 += 32; pb1 += 32;
        __syncthreads();
        short8 af[4], bfr[4];
#pragma unroll
        for (int mt = 0; mt < 4; ++mt)
            af[mt] = *reinterpret_cast<const short8*>(As + (wm * 4 + mt) * 1024 + lane * 16);
#pragma unroll
        for (int nt = 0; nt < 4; ++nt)
            bfr[nt] = *reinterpret_cast<const short8*>(Bs + (wn * 4 + nt) * 1024 + lane * 16);
#pragma unroll
        for (int mt = 0; mt < 4; ++mt)
#pragma unroll
            for (int nt = 0; nt < 4; ++nt)
                acc[mt][nt] = __builtin_amdgcn_mfma_f32_16x16x32_bf16(af[mt], bfr[nt], acc[mt][nt], 0, 0, 0);
    }

#pragma unroll
    for (int mt = 0; mt < 4; ++mt) {
        int rbase = (wm * 4 + mt) * 16 + ((lane >> 4) * 4);
#pragma unroll
        for (int r = 0; r < 4; ++r) {
            int row = rbase + r;
            if (m0 + row < Te) {
                float g = gts[row];
#pragma unroll
                for (int nt = 0; nt < 4; ++nt) {
                    int col = n0 + (wn * 4 + nt) * 16 + mcol;
                    y[(size_t)(hb + m0 + row) * DIN + col] = f2bf(acc[mt][nt][r] * g);
                }
            }
        }
    }
}

// ---------------- combine: out[t] = y[slot0] + y[slot1] ----------------
__global__ __launch_bounds__(256) void combine_kernel(
    const unsigned short* __restrict__ y, const int4* __restrict__ tokexp,
    const int* __restrict__ base, float* __restrict__ out)
{
    int t = blockIdx.x;
    int c = threadIdx.x * 4;
    int4 te = tokexp[t];
    const unsigned short* y0 = y + (size_t)(base[te.x] + te.y) * DIN + c;
    const unsigned short* y1 = y + (size_t)(base[te.z] + te.w) * DIN + c;
    us4 u0 = *reinterpret_cast<const us4*>(y0);
    us4 u1 = *reinterpret_cast<const us4*>(y1);
    float4 o;
    o.x = bf2f(u0.x) + bf2f(u1.x);
    o.y = bf2f(u0.y) + bf2f(u1.y);
    o.z = bf2f(u0.z) + bf2f(u1.z);
    o.w = bf2f(u0.w) + bf2f(u1.w);
    *reinterpret_cast<float4*>(out + (size_t)t * DIN + c) = o;
}

extern "C" void kernel_launch(void* const* d_in, const int* in_sizes, int n_in,
                              void* d_out, int out_size, void* d_ws, size_t ws_size,
                              hipStream_t stream) {
    const float* x  = (const float*)d_in[0];
    const float* Q  = (const float*)d_in[1];
    const float* K  = (const float*)d_in[2];
    const float* w1 = (const float*)d_in[3];
    const float* w2 = (const float*)d_in[4];
    float* out = (float*)d_out;

    char* ws = (char*)d_ws;
    int*   cnt       = (int*)(ws + OFF_CNT);
    int*   base      = (int*)(ws + OFF_BASE);
    int4*  tokexp    = (int4*)(ws + OFF_TOKEXP);
    int*   tok_list  = (int*)(ws + OFF_TOK);
    float* gate_list = (float*)(ws + OFF_GATE);
    unsigned short* xb  = (unsigned short*)(ws + OFF_XB);
    unsigned short* w1t = (unsigned short*)(ws + OFF_W1T);
    unsigned short* w2t = (unsigned short*)(ws + OFF_W2T);
    unsigned short* h   = (unsigned short*)(ws + OFF_H);
    unsigned short* y   = (unsigned short*)(ws + OFF_Y);

    hipMemsetAsync(ws + OFF_CNT, 0, 64, stream);

    convert_x_kernel<<<TT * DIN / (256 * 8), 256, 0, stream>>>(x, xb);
    convert_w_kernel<<<dim3(DIN / 32, DH / 32, NE), 256, 0, stream>>>(w1, w1t, DIN, DH);
    convert_w_kernel<<<dim3(DH / 32, DIN / 32, NE), 256, 0, stream>>>(w2, w2t, DH, DIN);
    gate_kernel<<<TT, 256, 0, stream>>>(Q, K, cnt, tok_list, gate_list, tokexp);
    scan_kernel<<<1, 64, 0, stream>>>(cnt, base);
    gemm1_kernel<<<dim3(TT / 128, DH / 128, NE), 256, 0, stream>>>(xb, w1t, cnt, base, tok_list, h);
    gemm2_kernel<<<dim3(TT / 128, DIN / 128, NE), 256, 0, stream>>>(h, w2t, cnt, base, gate_list, y);
    combine_kernel<<<TT, 256, 0, stream>>>(y, tokexp, base, out);
}

// Round 3
// 626.692 us; speedup vs baseline: 2.1978x; 1.1630x over previous
//
#include <hip/hip_runtime.h>
#include <math.h>

#define TT 8192   // tokens = B*P
#define NE 8      // experts
#define DIN 1024  // input size
#define DH 512    // hidden size

typedef __attribute__((ext_vector_type(8))) short short8;   // 8 bf16 = 4 VGPRs
typedef __attribute__((ext_vector_type(4))) float f32x4;
typedef __attribute__((ext_vector_type(4))) unsigned short us4;

// ---------------- workspace layout (bytes) ----------------
static const size_t OFF_CNT    = 0;                                      // int[8]
static const size_t OFF_BASE   = 256;                                    // int[8]
static const size_t OFF_TOKEXP = 512;                                    // int2[TT]
static const size_t OFF_GPAIR  = OFF_TOKEXP + (size_t)TT * 8;            // float2[TT]
static const size_t OFF_SLOT0  = OFF_GPAIR  + (size_t)TT * 8;            // int[TT]
static const size_t OFF_SLOT1  = OFF_SLOT0  + (size_t)TT * 4;            // int[TT]
static const size_t OFF_TOK    = OFF_SLOT1  + (size_t)TT * 4;            // int[NE][TT]
static const size_t OFF_GATE   = OFF_TOK    + (size_t)NE * TT * 4;       // float[NE][TT]
static const size_t OFF_XB     = OFF_GATE   + (size_t)NE * TT * 4;       // bf16[TT][DIN]
static const size_t OFF_W1T    = OFF_XB     + (size_t)TT * DIN * 2;      // bf16[NE][DH][DIN]
static const size_t OFF_W2T    = OFF_W1T    + (size_t)NE * DH * DIN * 2; // bf16[NE][DIN][DH]
static const size_t OFF_H      = OFF_W2T    + (size_t)NE * DIN * DH * 2; // bf16[2*TT][DH]
static const size_t OFF_Y      = OFF_H      + (size_t)2 * TT * DH * 2;   // bf16[2*TT][DIN]

__device__ __forceinline__ unsigned short f2bf(float f) {
    union { float f; unsigned u; } v; v.f = f;
    unsigned r = (v.u + 0x7fffu + ((v.u >> 16) & 1u)) >> 16;
    return (unsigned short)r;
}
__device__ __forceinline__ float bf2f(unsigned short u) {
    union { unsigned u; float f; } v; v.u = ((unsigned)u) << 16;
    return v.f;
}
__device__ __forceinline__ void async_copy16(const void* g, void* l) {
    __builtin_amdgcn_global_load_lds(
        (const __attribute__((address_space(1))) void*)g,
        (__attribute__((address_space(3))) void*)l, 16, 0, 0);
}

// ---------------- conversions ----------------
__global__ __launch_bounds__(256) void convert_x_kernel(const float* __restrict__ x,
                                                        unsigned short* __restrict__ xb)
{
    size_t i = ((size_t)blockIdx.x * 256 + threadIdx.x) * 8;
    float4 a = *reinterpret_cast<const float4*>(x + i);
    float4 b = *reinterpret_cast<const float4*>(x + i + 4);
    us4 o0 = { f2bf(a.x), f2bf(a.y), f2bf(a.z), f2bf(a.w) };
    us4 o1 = { f2bf(b.x), f2bf(b.y), f2bf(b.z), f2bf(b.w) };
    *reinterpret_cast<us4*>(xb + i)     = o0;
    *reinterpret_cast<us4*>(xb + i + 4) = o1;
}

// src [E][K][N] fp32 -> dst [E][N][K] bf16
__global__ __launch_bounds__(256) void convert_w_kernel(const float* __restrict__ src,
                                                        unsigned short* __restrict__ dst,
                                                        int K, int N)
{
    int e = blockIdx.z;
    int k0 = blockIdx.x * 32, n0 = blockIdx.y * 32;
    __shared__ float tile[32][33];
    int tx = threadIdx.x & 31, ty = threadIdx.x >> 5;
    const float* s = src + ((size_t)e * K + k0) * N + n0;
#pragma unroll
    for (int r = 0; r < 32; r += 8) tile[ty + r][tx] = s[(size_t)(ty + r) * N + tx];
    __syncthreads();
    unsigned short* d = dst + ((size_t)e * N + n0) * K + k0;
#pragma unroll
    for (int r = 0; r < 32; r += 8) d[(size_t)(ty + r) * K + tx] = f2bf(tile[tx][ty + r]);
}

// ---------------- gating: one wave per token, no atomics ----------------
__global__ __launch_bounds__(256) void gate_kernel(
    const float* __restrict__ Q, const float* __restrict__ Kc,
    int2* __restrict__ tokexp, float2* __restrict__ gpair)
{
    int wave = threadIdx.x >> 6, lane = threadIdx.x & 63;
    int t = blockIdx.x * 4 + wave;
    const float4* q4 = reinterpret_cast<const float4*>(Q + (size_t)t * DIN);
    const float4* k4 = reinterpret_cast<const float4*>(Kc + (size_t)t * NE * DIN);
    float4 q[4];
#pragma unroll
    for (int j = 0; j < 4; ++j) q[j] = q4[j * 64 + lane];
    float part[NE];
#pragma unroll
    for (int e = 0; e < NE; ++e) {
        float s = 0.0f;
#pragma unroll
        for (int j = 0; j < 4; ++j) {
            float4 kv = k4[e * 256 + j * 64 + lane];
            s += q[j].x * kv.x + q[j].y * kv.y + q[j].z * kv.z + q[j].w * kv.w;
        }
        part[e] = s;
    }
#pragma unroll
    for (int e = 0; e < NE; ++e) {
#pragma unroll
        for (int m = 1; m < 64; m <<= 1) part[e] += __shfl_xor(part[e], m);
    }
    if (lane == 0) {
        float s[NE];
#pragma unroll
        for (int e = 0; e < NE; ++e) {
            float v = part[e] * 0.03125f;
            if (isnan(v)) v = 0.0f;
            else if (isinf(v)) v = (v > 0.0f) ? 20.0f : -20.0f;
            s[e] = v;
        }
        float m = s[0];
        for (int e = 1; e < NE; ++e) m = fmaxf(m, s[e]);
        float p[NE]; float sum = 0.0f;
        for (int e = 0; e < NE; ++e) { p[e] = expf(s[e] - m); sum += p[e]; }
        float inv = 1.0f / sum;
        for (int e = 0; e < NE; ++e) p[e] *= inv;
        int i0 = 0;
        for (int e = 1; e < NE; ++e) if (p[e] > p[i0]) i0 = e;
        int i1 = (i0 == 0) ? 1 : 0;
        for (int e = 0; e < NE; ++e) if (e != i0 && p[e] > p[i1]) i1 = e;
        float denom = p[i0] + p[i1] + 1e-6f;
        tokexp[t] = make_int2(i0, i1);
        gpair[t]  = make_float2(p[i0] / denom, p[i1] / denom);
    }
}

// ---------------- routing: count / scan / build (atomic-free) ----------------
__global__ __launch_bounds__(1024) void count_kernel(const int2* __restrict__ tokexp,
                                                     int* __restrict__ cnt)
{
    int e = blockIdx.x;
    int tid = threadIdx.x;
    int local = 0;
#pragma unroll
    for (int r = 0; r < TT / 1024; ++r) {
        int2 te = tokexp[r * 1024 + tid];
        local += (te.x == e || te.y == e) ? 1 : 0;
    }
#pragma unroll
    for (int m = 1; m < 64; m <<= 1) local += __shfl_xor(local, m);
    __shared__ int wsum[16];
    int wave = tid >> 6, lane = tid & 63;
    if (lane == 0) wsum[wave] = local;
    __syncthreads();
    if (tid == 0) {
        int s = 0;
        for (int w = 0; w < 16; ++w) s += wsum[w];
        cnt[e] = s;
    }
}

__global__ void scan_kernel(const int* __restrict__ cnt, int* __restrict__ base)
{
    if (threadIdx.x == 0) {
        int s = 0;
        for (int e = 0; e < NE; ++e) { base[e] = s; s += cnt[e]; }
    }
}

__global__ __launch_bounds__(1024) void build_kernel(
    const int2* __restrict__ tokexp, const float2* __restrict__ gpair,
    const int* __restrict__ base,
    int* __restrict__ tok_list, float* __restrict__ gate_list,
    int* __restrict__ slot0, int* __restrict__ slot1)
{
    int e = blockIdx.x;
    int tid = threadIdx.x;
    int wave = tid >> 6, lane = tid & 63;
    __shared__ int wsum[16];
    __shared__ int running;
    if (tid == 0) running = base[e];
    __syncthreads();
    int eb = base[e];
#pragma unroll 1
    for (int r = 0; r < TT / 1024; ++r) {
        int t = r * 1024 + tid;
        int2 te = tokexp[t];
        float2 g = gpair[t];
        bool f0 = (te.x == e), f1 = (te.y == e);
        bool f = f0 || f1;
        unsigned long long mask = __ballot(f);
        int mypos = __popcll(mask & ((1ull << lane) - 1ull));
        if (lane == 0) wsum[wave] = __popcll(mask);
        __syncthreads();
        int off = 0, total = 0;
        for (int w = 0; w < 16; ++w) {
            int c = wsum[w];
            if (w < wave) off += c;
            total += c;
        }
        int pos = running + off + mypos;
        if (f) {
            int j = pos - eb;
            tok_list[e * TT + j]  = t;
            gate_list[e * TT + j] = f0 ? g.x : g.y;
            if (f0) slot0[t] = pos; else slot1[t] = pos;
        }
        __syncthreads();
        if (tid == 0) running += total;
        __syncthreads();
    }
}

// ---------------- GEMM1: h = gelu(gather(xb) @ w1t^T), bf16 MFMA ----------------
__global__ __launch_bounds__(256) void gemm1_kernel(
    const unsigned short* __restrict__ xb, const unsigned short* __restrict__ w1t,
    const int* __restrict__ cnt, const int* __restrict__ base,
    const int* __restrict__ tok_list, unsigned short* __restrict__ h)
{
    int e = blockIdx.z;
    int Te = cnt[e];
    int m0 = blockIdx.x * 128;
    if (m0 >= Te) return;
    int n0 = blockIdx.y * 128;

    __shared__ __align__(16) char smem[16384];   // A: 8x1024B, B: 8x1024B
    __shared__ int rows[128];
    char* As = smem;
    char* Bs = smem + 8192;

    int tid = threadIdx.x;
    if (tid < 128) rows[tid] = (m0 + tid < Te) ? tok_list[e * TT + m0 + tid] : 0;
    __syncthreads();

    int w = tid >> 6, lane = tid & 63;
    int wm = w & 1, wn = w >> 1;
    int mcol = lane & 15;
    int kq = (lane >> 4) * 8;

    const unsigned short* w1e = w1t + (size_t)e * DH * DIN;
    const unsigned short* pa0 = xb + (size_t)rows[(2 * w + 0) * 16 + mcol] * DIN + kq;
    const unsigned short* pa1 = xb + (size_t)rows[(2 * w + 1) * 16 + mcol] * DIN + kq;
    const unsigned short* pb0 = w1e + (size_t)(n0 + (2 * w + 0) * 16 + mcol) * DIN + kq;
    const unsigned short* pb1 = w1e + (size_t)(n0 + (2 * w + 1) * 16 + mcol) * DIN + kq;
    char* dA0 = As + (2 * w + 0) * 1024;
    char* dA1 = As + (2 * w + 1) * 1024;
    char* dB0 = Bs + (2 * w + 0) * 1024;
    char* dB1 = Bs + (2 * w + 1) * 1024;

    f32x4 acc[4][4];
#pragma unroll
    for (int i = 0; i < 4; i++)
#pragma unroll
        for (int j = 0; j < 4; j++) acc[i][j] = {0.f, 0.f, 0.f, 0.f};

    for (int k0 = 0; k0 < DIN; k0 += 32) {
        __syncthreads();
        async_copy16(pa0, dA0); async_copy16(pa1, dA1);
        async_copy16(pb0, dB0); async_copy16(pb1, dB1);
        pa0 += 32; pa1 += 32; pb0 += 32; pb1 += 32;
        __syncthreads();
        short8 af[4], bfr[4];
#pragma unroll
        for (int mt = 0; mt < 4; ++mt)
            af[mt] = *reinterpret_cast<const short8*>(As + (wm * 4 + mt) * 1024 + lane * 16);
#pragma unroll
        for (int nt = 0; nt < 4; ++nt)
            bfr[nt] = *reinterpret_cast<const short8*>(Bs + (wn * 4 + nt) * 1024 + lane * 16);
#pragma unroll
        for (int mt = 0; mt < 4; ++mt)
#pragma unroll
            for (int nt = 0; nt < 4; ++nt)
                acc[mt][nt] = __builtin_amdgcn_mfma_f32_16x16x32_bf16(af[mt], bfr[nt], acc[mt][nt], 0, 0, 0);
    }

    int hb = base[e] + m0;
#pragma unroll
    for (int mt = 0; mt < 4; ++mt) {
        int rbase = (wm * 4 + mt) * 16 + ((lane >> 4) * 4);
#pragma unroll
        for (int r = 0; r < 4; ++r) {
            int row = rbase + r;
            if (m0 + row < Te) {
#pragma unroll
                for (int nt = 0; nt < 4; ++nt) {
                    float u = acc[mt][nt][r];
                    float g = 0.5f * u * (1.0f + erff(u * 0.70710678118f));
                    int col = n0 + (wn * 4 + nt) * 16 + mcol;
                    h[(size_t)(hb + row) * DH + col] = f2bf(g);
                }
            }
        }
    }
}

// ---------------- GEMM2: y = gate * (h @ w2t^T), bf16 MFMA ----------------
__global__ __launch_bounds__(256) void gemm2_kernel(
    const unsigned short* __restrict__ h, const unsigned short* __restrict__ w2t,
    const int* __restrict__ cnt, const int* __restrict__ base,
    const float* __restrict__ gate_list, unsigned short* __restrict__ y)
{
    int e = blockIdx.z;
    int Te = cnt[e];
    int m0 = blockIdx.x * 128;
    if (m0 >= Te) return;
    int n0 = blockIdx.y * 128;

    __shared__ __align__(16) char smem[16384];
    __shared__ float gts[128];
    char* As = smem;
    char* Bs = smem + 8192;

    int tid = threadIdx.x;
    if (tid < 128) gts[tid] = (m0 + tid < Te) ? gate_list[e * TT + m0 + tid] : 0.0f;

    int w = tid >> 6, lane = tid & 63;
    int wm = w & 1, wn = w >> 1;
    int mcol = lane & 15;
    int kq = (lane >> 4) * 8;
    int hb = base[e];

    int r0 = m0 + (2 * w + 0) * 16 + mcol; if (r0 >= Te) r0 = Te - 1;
    int r1 = m0 + (2 * w + 1) * 16 + mcol; if (r1 >= Te) r1 = Te - 1;
    const unsigned short* w2e = w2t + (size_t)e * DIN * DH;
    const unsigned short* pa0 = h + (size_t)(hb + r0) * DH + kq;
    const unsigned short* pa1 = h + (size_t)(hb + r1) * DH + kq;
    const unsigned short* pb0 = w2e + (size_t)(n0 + (2 * w + 0) * 16 + mcol) * DH + kq;
    const unsigned short* pb1 = w2e + (size_t)(n0 + (2 * w + 1) * 16 + mcol) * DH + kq;
    char* dA0 = As + (2 * w + 0) * 1024;
    char* dA1 = As + (2 * w + 1) * 1024;
    char* dB0 = Bs + (2 * w + 0) * 1024;
    char* dB1 = Bs + (2 * w + 1) * 1024;

    f32x4 acc[4][4];
#pragma unroll
    for (int i = 0; i < 4; i++)
#pragma unroll
        for (int j = 0; j < 4; j++) acc[i][j] = {0.f, 0.f, 0.f, 0.f};

    for (int k0 = 0; k0 < DH; k0 += 32) {
        __syncthreads();
        async_copy16(pa0, dA0); async_copy16(pa1, dA1);
        async_copy16(pb0, dB0); async_copy16(pb1, dB1);
        pa0 += 32; pa1 += 32; pb0 += 32; pb1 += 32;
        __syncthreads();
        short8 af[4], bfr[4];
#pragma unroll
        for (int mt = 0; mt < 4; ++mt)
            af[mt] = *reinterpret_cast<const short8*>(As + (wm * 4 + mt) * 1024 + lane * 16);
#pragma unroll
        for (int nt = 0; nt < 4; ++nt)
            bfr[nt] = *reinterpret_cast<const short8*>(Bs + (wn * 4 + nt) * 1024 + lane * 16);
#pragma unroll
        for (int mt = 0; mt < 4; ++mt)
#pragma unroll
            for (int nt = 0; nt < 4; ++nt)
                acc[mt][nt] = __builtin_amdgcn_mfma_f32_16x16x32_bf16(af[mt], bfr[nt], acc[mt][nt], 0, 0, 0);
    }

#pragma unroll
    for (int mt = 0; mt < 4; ++mt) {
        int rbase = (wm * 4 + mt) * 16 + ((lane >> 4) * 4);
#pragma unroll
        for (int r = 0; r < 4; ++r) {
            int row = rbase + r;
            if (m0 + row < Te) {
                float g = gts[row];
#pragma unroll
                for (int nt = 0; nt < 4; ++nt) {
                    int col = n0 + (wn * 4 + nt) * 16 + mcol;
                    y[(size_t)(hb + m0 + row) * DIN + col] = f2bf(acc[mt][nt][r] * g);
                }
            }
        }
    }
}

// ---------------- combine: out[t] = y[slot0[t]] + y[slot1[t]] ----------------
__global__ __launch_bounds__(256) void combine_kernel(
    const unsigned short* __restrict__ y,
    const int* __restrict__ slot0, const int* __restrict__ slot1,
    float* __restrict__ out)
{
    int t = blockIdx.x;
    int c = threadIdx.x * 4;
    const unsigned short* y0 = y + (size_t)slot0[t] * DIN + c;
    const unsigned short* y1 = y + (size_t)slot1[t] * DIN + c;
    us4 u0 = *reinterpret_cast<const us4*>(y0);
    us4 u1 = *reinterpret_cast<const us4*>(y1);
    float4 o;
    o.x = bf2f(u0.x) + bf2f(u1.x);
    o.y = bf2f(u0.y) + bf2f(u1.y);
    o.z = bf2f(u0.z) + bf2f(u1.z);
    o.w = bf2f(u0.w) + bf2f(u1.w);
    *reinterpret_cast<float4*>(out + (size_t)t * DIN + c) = o;
}

extern "C" void kernel_launch(void* const* d_in, const int* in_sizes, int n_in,
                              void* d_out, int out_size, void* d_ws, size_t ws_size,
                              hipStream_t stream) {
    const float* x  = (const float*)d_in[0];
    const float* Q  = (const float*)d_in[1];
    const float* K  = (const float*)d_in[2];
    const float* w1 = (const float*)d_in[3];
    const float* w2 = (const float*)d_in[4];
    float* out = (float*)d_out;

    char* ws = (char*)d_ws;
    int*    cnt       = (int*)(ws + OFF_CNT);
    int*    base      = (int*)(ws + OFF_BASE);
    int2*   tokexp    = (int2*)(ws + OFF_TOKEXP);
    float2* gpair     = (float2*)(ws + OFF_GPAIR);
    int*    slot0     = (int*)(ws + OFF_SLOT0);
    int*    slot1     = (int*)(ws + OFF_SLOT1);
    int*    tok_list  = (int*)(ws + OFF_TOK);
    float*  gate_list = (float*)(ws + OFF_GATE);
    unsigned short* xb  = (unsigned short*)(ws + OFF_XB);
    unsigned short* w1t = (unsigned short*)(ws + OFF_W1T);
    unsigned short* w2t = (unsigned short*)(ws + OFF_W2T);
    unsigned short* h   = (unsigned short*)(ws + OFF_H);
    unsigned short* y   = (unsigned short*)(ws + OFF_Y);

    convert_x_kernel<<<TT * DIN / (256 * 8), 256, 0, stream>>>(x, xb);
    convert_w_kernel<<<dim3(DIN / 32, DH / 32, NE), 256, 0, stream>>>(w1, w1t, DIN, DH);
    convert_w_kernel<<<dim3(DH / 32, DIN / 32, NE), 256, 0, stream>>>(w2, w2t, DH, DIN);
    gate_kernel<<<TT / 4, 256, 0, stream>>>(Q, K, tokexp, gpair);
    count_kernel<<<NE, 1024, 0, stream>>>(tokexp, cnt);
    scan_kernel<<<1, 64, 0, stream>>>(cnt, base);
    build_kernel<<<NE, 1024, 0, stream>>>(tokexp, gpair, base, tok_list, gate_list, slot0, slot1);
    gemm1_kernel<<<dim3(TT / 128, DH / 128, NE), 256, 0, stream>>>(xb, w1t, cnt, base, tok_list, h);
    gemm2_kernel<<<dim3(TT / 128, DIN / 128, NE), 256, 0, stream>>>(h, w2t, cnt, base, gate_list, y);
    combine_kernel<<<TT, 256, 0, stream>>>(y, slot0, slot1, out);
}